// Round 12
// baseline (181.189 us; speedup 1.0000x reference)
//
#include <hip/hip_runtime.h>
#include <hip/hip_bf16.h>

typedef __attribute__((ext_vector_type(8))) short short8;
typedef __attribute__((ext_vector_type(4))) short bf16x4;
typedef __attribute__((ext_vector_type(4))) float f32x4;

#define TT 2048   // sequence length
#define DM 1024   // model dim
#define NH 16     // query heads
#define NKV 4     // kv heads
#define HD 64     // head dim

#define MFMA32(a,b,c) __builtin_amdgcn_mfma_f32_16x16x32_bf16(a,b,c,0,0,0)
#define MFMA16(a,b,c) __builtin_amdgcn_mfma_f32_16x16x16bf16_1k(a,b,c,0,0,0)

__device__ __forceinline__ unsigned short f2bf(float x){
  unsigned int u = __float_as_uint(x);
  u += 0x7fffu + ((u >> 16) & 1u);   // RNE
  return (unsigned short)(u >> 16);
}
// packed 2xfp32 -> 2xbf16 (v_cvt_pk_bf16_f32 on gfx950)
__device__ __forceinline__ unsigned int pkbf2(float x, float y){
  union { __hip_bfloat162 h; unsigned int u; } t;
  t.h = __float22bfloat162_rn(make_float2(x, y));
  return t.u;
}
// async global->LDS, 16B/lane; GLOBAL addr is PER-LANE, lds dest = uniform base + lane*16
__device__ __forceinline__ void gl_lds16(const unsigned short* g, unsigned short* l){
  __builtin_amdgcn_global_load_lds(
      (__attribute__((address_space(1))) void*)g,
      (__attribute__((address_space(3))) void*)l, 16, 0, 0);
}

// ---------------- 1. x + weights fp32 -> bf16 ----------------
__global__ __launch_bounds__(256) void convertw_kernel(
    const float* __restrict__ x,
    const float* __restrict__ qw, const float* __restrict__ kw,
    const float* __restrict__ vw, const float* __restrict__ ow,
    unsigned short* __restrict__ xb,
    unsigned short* __restrict__ wqkv, unsigned short* __restrict__ owb){
  long v = (long)blockIdx.x * 256 + threadIdx.x;
  const float* src; unsigned short* dst; long base;
  if      (v < 524288) { src = x;  dst = xb;             base = v; }
  else if (v < 786432) { src = qw; dst = wqkv;           base = v - 524288; }
  else if (v < 851968) { src = kw; dst = wqkv + 1048576; base = v - 786432; }
  else if (v < 917504) { src = vw; dst = wqkv + 1310720; base = v - 851968; }
  else                 { src = ow; dst = owb;            base = v - 917504; }
  f32x4 d = *(const f32x4*)(src + base * 4);
  uint2 pk = { pkbf2(d[0], d[1]), pkbf2(d[2], d[3]) };
  *(uint2*)(dst + base * 4) = pk;
}

// ---------------- 2. QKV GEMM (async LDS staging) + fused RMSNorm/RoPE/q0k0 ----------
// grid dim3(24, 32): x = head-block (0..15 q | 16..19 k | 20..23 v), y = 64-row t-tile
// K written PRE-FRAGMENTED: kbf[(kvh*64+tile32)*4 + frag][lane][8]  (frag-major, 4KB/tile)
//   frag f, lane l, j  ->  K[key=(f>>1)*16 + (l&15)][d=(f&1)*32 + (l>>4)*8 + j]
// V written PRE-FRAGMENTED: vtf[(kvh*128+tile16)*4 + dt][lane][4]   (2KB/tile16)
//   dt, lane l, r      ->  V[d=dt*16 + (l&15)][key=tile16*16 + (l>>4)*4 + r]
__global__ __launch_bounds__(256) void gemm1_fused(
    const unsigned short* __restrict__ xb, const unsigned short* __restrict__ wqkv,
    unsigned short* __restrict__ qb, unsigned short* __restrict__ kbf,
    unsigned short* __restrict__ vtf,
    float* __restrict__ q0, float* __restrict__ k0,
    float* __restrict__ bpart, const float* __restrict__ curv){
  __shared__ __align__(16) unsigned short As[2 * 64 * 32];  // 8 KB (k lo/hi)
  __shared__ __align__(16) unsigned short Bs[2 * 64 * 32];  // 8 KB
  __shared__ float Ct[64 * 65];                             // 16.6 KB epilogue
  __shared__ float bsum;
  const int tid = threadIdx.x, lane = tid & 63, wave = tid >> 6;
  const int hIdx = blockIdx.x;
  const int bm = blockIdx.y * 64, bn = hIdx * 64;
  const int wm = (wave >> 1) * 32, wn = (wave & 1) * 32;
  const int ml = lane & 15, quad = lane >> 4;
  if (tid == 0) bsum = 0.f;
  f32x4 acc[2][2];
  const f32x4 z = {0.f, 0.f, 0.f, 0.f};
  acc[0][0] = z; acc[0][1] = z; acc[1][0] = z; acc[1][1] = z;

  const int srow = wave * 16 + (lane >> 2), scol = (lane & 3) * 8;
  const unsigned short* Ag = xb   + (long)(bm + srow) * 1024 + scol;
  const unsigned short* Bg = wqkv + (long)(bn + srow) * 1024 + scol;
  unsigned short* Al0 = As + wave * 512;
  unsigned short* Al1 = As + 2048 + wave * 512;
  unsigned short* Bl0 = Bs + wave * 512;
  unsigned short* Bl1 = Bs + 2048 + wave * 512;

  for (int kk = 0; kk < 1024; kk += 64){
    __syncthreads();
    gl_lds16(Ag + kk,      Al0);
    gl_lds16(Ag + kk + 32, Al1);
    gl_lds16(Bg + kk,      Bl0);
    gl_lds16(Bg + kk + 32, Bl1);
    __syncthreads();   // compiler drains vmcnt before barrier
#pragma unroll
    for (int half = 0; half < 2; half++){
      const unsigned short* Ah = As + half * 2048;
      const unsigned short* Bh = Bs + half * 2048;
      short8 a0f = *(const short8*)&Ah[(wm + ml) * 32 + quad * 8];
      short8 a1f = *(const short8*)&Ah[(wm + 16 + ml) * 32 + quad * 8];
      short8 b0f = *(const short8*)&Bh[(wn + ml) * 32 + quad * 8];
      short8 b1f = *(const short8*)&Bh[(wn + 16 + ml) * 32 + quad * 8];
      acc[0][0] = MFMA32(a0f, b0f, acc[0][0]);
      acc[0][1] = MFMA32(a0f, b1f, acc[0][1]);
      acc[1][0] = MFMA32(a1f, b0f, acc[1][0]);
      acc[1][1] = MFMA32(a1f, b1f, acc[1][1]);
    }
  }
  __syncthreads();
#pragma unroll
  for (int i = 0; i < 2; i++)
#pragma unroll
    for (int j = 0; j < 2; j++)
#pragma unroll
      for (int r = 0; r < 4; r++)
        Ct[(wm + i * 16 + quad * 4 + r) * 65 + wn + j * 16 + ml] = acc[i][j][r];
  __syncthreads();

  if (hIdx < 20){
    // RMSNorm + RoPE + q0/k0 (+ spatial partial for q). lane = head-dim d.
    const bool isq = hIdx < 16;
    const int h = isq ? hIdx : hIdx - 16;
    const float c = curv[0];
    float* o0 = isq ? q0 : k0;
#pragma unroll 1
    for (int rr = 0; rr < 16; rr++){
      const int row = wave * 16 + rr;
      const int t = bm + row;
      float val = Ct[row * 65 + lane];
      float ss = val * val;
#pragma unroll
      for (int off = 1; off < 64; off <<= 1) ss += __shfl_xor(ss, off);
      float scale = __builtin_amdgcn_rsqf(ss * (1.f / 64.f) + 1e-6f);
      float xn = val * scale;
      float other = __shfl_xor(xn, 32);
      int fi = lane & 31;
      float ang = (float)t * __builtin_amdgcn_exp2f((float)fi * (-13.287712379549449f / 32.f));
      float sn, cs; __sincosf(ang, &sn, &cs);
      float outv = (lane < 32) ? (xn * cs + other * sn) : (xn * cs - other * sn);
      if (isq){
        qb[((long)h * TT + t) * 64 + lane] = f2bf(outv);
      } else {
        // pre-fragmented K write
        const int w = t & 31, tile = t >> 5;
        const int f = ((w >> 4) << 1) | (lane >> 5);
        const int kch = (lane & 31) >> 3, j = lane & 7;
        kbf[(((long)(h * 64 + tile) * 4 + f) * 64 + (w & 15) + kch * 16) * 8 + j] = f2bf(outv);
      }
      if (lane == 0){
        float sq = ss * scale * scale;      // |normed|^2, rope preserves norm
        o0[h * TT + t] = __builtin_amdgcn_sqrtf(1.f / c + sq);
        if (isq) atomicAdd(&bsum, __builtin_amdgcn_sqrtf(sq));
      }
    }
  } else {
    // V: bf16 + pre-fragmented write vtf[(hk*128+tile16)*4+dt][lane][4]
    const int hk = hIdx - 20;
    const int d = tid >> 2, tseg = (tid & 3) * 16;
    uint4 w0, w1;
    w0.x = pkbf2(Ct[(tseg + 0) * 65 + d], Ct[(tseg + 1) * 65 + d]);
    w0.y = pkbf2(Ct[(tseg + 2) * 65 + d], Ct[(tseg + 3) * 65 + d]);
    w0.z = pkbf2(Ct[(tseg + 4) * 65 + d], Ct[(tseg + 5) * 65 + d]);
    w0.w = pkbf2(Ct[(tseg + 6) * 65 + d], Ct[(tseg + 7) * 65 + d]);
    w1.x = pkbf2(Ct[(tseg + 8) * 65 + d], Ct[(tseg + 9) * 65 + d]);
    w1.y = pkbf2(Ct[(tseg +10) * 65 + d], Ct[(tseg +11) * 65 + d]);
    w1.z = pkbf2(Ct[(tseg +12) * 65 + d], Ct[(tseg +13) * 65 + d]);
    w1.w = pkbf2(Ct[(tseg +14) * 65 + d], Ct[(tseg +15) * 65 + d]);
    const int tile16 = (bm + tseg) >> 4;
    const int dt = d >> 4, mlv = d & 15;
    unsigned short* vb = vtf + ((long)(hk * 128 + tile16) * 4 + dt) * 256;
    *(uint2*)&vb[(mlv +  0) * 4] = make_uint2(w0.x, w0.y);
    *(uint2*)&vb[(mlv + 16) * 4] = make_uint2(w0.z, w0.w);
    *(uint2*)&vb[(mlv + 32) * 4] = make_uint2(w1.x, w1.y);
    *(uint2*)&vb[(mlv + 48) * 4] = make_uint2(w1.z, w1.w);
  }
  __syncthreads();
  if (tid == 0) bpart[blockIdx.y * 24 + hIdx] = bsum;
}

// ---------------- 3. 4-head LDS-staged hyperbolic causal attention ----------
// block = 256 thr (4 waves): one q-tile qt (longest-first), one kvh; wave w owns head
// kvh*4+w completely (no cross-wave merge). Per 32-key j-tile the block DMA-stages
// K(4KB)+V(4KB) once via global_load_lds (dense, pre-fragmented, PER-LANE global addr),
// all 4 waves consume from LDS.
// S^T = mfma_16x16x32(K,Q): C layout (key=quad*4+r, q=ml) == B-fragment of
// mfma_16x16x16 -> in-lane transform+pack, no cross-lane ops in the loop.
__global__ __launch_bounds__(256, 4) void attn_kernel(
    const unsigned short* __restrict__ qb_, const unsigned short* __restrict__ kbf,
    const unsigned short* __restrict__ vtf,
    const float* __restrict__ q0_, const float* __restrict__ k0_,
    const float* __restrict__ temp, const float* __restrict__ curv,
    unsigned short* __restrict__ attn_out,
    const float* __restrict__ bpart, float* __restrict__ out_scalar){
  __shared__ __align__(16) unsigned short Ksm[2048];   // 4KB: frag-major K tile
  __shared__ __align__(16) unsigned short Vsm[2048];   // 4KB: two frag-major V tile16s
  const int tid = threadIdx.x, lane = tid & 63, wave = tid >> 6;
  const int qt  = 127 - (blockIdx.x >> 2);     // longest-first
  const int kvh = blockIdx.x & 3;
  const int h   = kvh * 4 + wave;              // wave owns this head
  const int i0  = qt * 16;
  const int ml = lane & 15, quad = lane >> 4;
  const float c = curv[0];
  const float fac = -__builtin_amdgcn_rsqf(c) / temp[h];
  const f32x4 z = {0.f, 0.f, 0.f, 0.f};
  const unsigned short* Kg = kbf + (long)kvh * 64 * 2048;   // [tile32][frag][lane][8]
  const unsigned short* Vg = vtf + (long)kvh * 128 * 1024;  // [tile16][dt][lane][4]
  const float* k0h = k0_ + kvh * TT;

  short8 qf0 = *(const short8*)&qb_[((long)h * TT + i0 + ml) * 64 + quad * 8];
  short8 qf1 = *(const short8*)&qb_[((long)h * TT + i0 + ml) * 64 + 32 + quad * 8];
  const float q0c = c * q0_[h * TT + i0 + ml];   // per-lane: q = i0+ml
  const int rowq = i0 + ml;

  f32x4 oa[4];
#pragma unroll
  for (int dt = 0; dt < 4; dt++) oa[dt] = z;
  float l_sum = 0.f;

  const int nt = (i0 + 47) >> 5;   // 32-key tiles

#pragma unroll 1
  for (int t = 0; t < nt; t++){
    const int j0 = t << 5;
    __syncthreads();    // previous iteration's LDS reads complete
    gl_lds16(Kg + (long)t * 2048 + wave * 512 + lane * 8, Ksm + wave * 512);
    gl_lds16(Vg + (long)t * 2048 + wave * 512 + lane * 8, Vsm + wave * 512);
    __syncthreads();    // DMA drained (compiler emits vmcnt(0))
    short8 ka0 = *(const short8*)&Ksm[        lane * 8];
    short8 ka1 = *(const short8*)&Ksm[ 512 + lane * 8];
    short8 kc0 = *(const short8*)&Ksm[1024 + lane * 8];
    short8 kc1 = *(const short8*)&Ksm[1536 + lane * 8];
    bf16x4 vfa0 = *(const bf16x4*)&Vsm[          lane * 4];
    bf16x4 vfa1 = *(const bf16x4*)&Vsm[ 256 +  lane * 4];
    bf16x4 vfa2 = *(const bf16x4*)&Vsm[ 512 +  lane * 4];
    bf16x4 vfa3 = *(const bf16x4*)&Vsm[ 768 +  lane * 4];
    bf16x4 vfb0 = *(const bf16x4*)&Vsm[1024 +  lane * 4];
    bf16x4 vfb1 = *(const bf16x4*)&Vsm[1280 +  lane * 4];
    bf16x4 vfb2 = *(const bf16x4*)&Vsm[1536 +  lane * 4];
    bf16x4 vfb3 = *(const bf16x4*)&Vsm[1792 +  lane * 4];
    f32x4 k0a = *(const f32x4*)(k0h + j0 + quad * 4);
    f32x4 k0b = *(const f32x4*)(k0h + j0 + 16 + quad * 4);

    f32x4 s0 = z, s1 = z;     // S^T: key=j0(+16)+quad*4+r, q=ml
    s0 = MFMA32(ka0, qf0, s0);
    s0 = MFMA32(ka1, qf1, s0);
    s1 = MFMA32(kc0, qf0, s1);
    s1 = MFMA32(kc1, qf1, s1);

    const bool nm = (j0 + 31 > i0);
    const int keyb = j0 + quad * 4;
    float p0[4], p1[4];
#pragma unroll
    for (int r = 0; r < 4; r++){
      float argA = fmaxf(__builtin_fmaf(-c, s0[r], q0c * k0a[r]), 1.00001f);
      float wA   = argA + __builtin_amdgcn_sqrtf(__builtin_fmaf(argA, argA, -1.f));
      float pA   = __builtin_amdgcn_exp2f(fac * __builtin_amdgcn_logf(wA));
      float argB = fmaxf(__builtin_fmaf(-c, s1[r], q0c * k0b[r]), 1.00001f);
      float wB   = argB + __builtin_amdgcn_sqrtf(__builtin_fmaf(argB, argB, -1.f));
      float pB   = __builtin_amdgcn_exp2f(fac * __builtin_amdgcn_logf(wB));
      if (nm){
        if (keyb + r > rowq)      pA = 0.f;
        if (keyb + 16 + r > rowq) pB = 0.f;
      }
      p0[r] = pA; p1[r] = pB;
      l_sum += pA + pB;
    }
    uint2 pua = { pkbf2(p0[0], p0[1]), pkbf2(p0[2], p0[3]) };
    uint2 pub = { pkbf2(p1[0], p1[1]), pkbf2(p1[2], p1[3]) };
    bf16x4 pfa = *(bf16x4*)&pua;    // B-fragment of 16x16x16, directly
    bf16x4 pfb = *(bf16x4*)&pub;
    oa[0] = MFMA16(vfa0, pfa, oa[0]);
    oa[1] = MFMA16(vfa1, pfa, oa[1]);
    oa[2] = MFMA16(vfa2, pfa, oa[2]);
    oa[3] = MFMA16(vfa3, pfa, oa[3]);
    oa[0] = MFMA16(vfb0, pfb, oa[0]);
    oa[1] = MFMA16(vfb1, pfb, oa[1]);
    oa[2] = MFMA16(vfb2, pfb, oa[2]);
    oa[3] = MFMA16(vfb3, pfb, oa[3]);
  }
  // l across quads (keys split over quads/regs; q=ml fixed)
  l_sum += __shfl_xor(l_sum, 16);
  l_sum += __shfl_xor(l_sum, 32);
  const float invL = __builtin_amdgcn_rcpf(l_sum);
  // direct epilogue: lane(ml,quad) holds O^T for q=i0+ml, d=dt*16+quad*4+r
#pragma unroll
  for (int dt = 0; dt < 4; dt++){
    uint2 o = { pkbf2(oa[dt][0] * invL, oa[dt][1] * invL),
                pkbf2(oa[dt][2] * invL, oa[dt][3] * invL) };
    *(uint2*)&attn_out[(long)(i0 + ml) * 1024 + h * 64 + dt * 16 + quad * 4] = o;
  }
  // fused spatial_norm finalize
  if (blockIdx.x == 0 && tid < 64){
    float s = 0.f;
    for (int i = lane; i < 768; i += 64) s += bpart[i];
#pragma unroll
    for (int off = 1; off < 64; off <<= 1) s += __shfl_xor(s, off);
    if (lane == 0) out_scalar[0] = s * (1.f / 32768.f);
  }
}

// ---------------- 4. O-proj GEMM (async LDS staging): out = attn x owb^T --------------
__global__ __launch_bounds__(256) void gemm2_kernel(
    const unsigned short* __restrict__ A, const unsigned short* __restrict__ B,
    float* __restrict__ C){
  __shared__ __align__(16) unsigned short As[2 * 64 * 32];
  __shared__ __align__(16) unsigned short Bs[2 * 64 * 32];
  const int tid = threadIdx.x, lane = tid & 63, wave = tid >> 6;
  const int bm = blockIdx.y * 64, bn = blockIdx.x * 64;
  const int wm = (wave >> 1) * 32, wn = (wave & 1) * 32;
  const int ml = lane & 15, quad = lane >> 4;
  f32x4 acc[2][2];
  const f32x4 z = {0.f, 0.f, 0.f, 0.f};
  acc[0][0] = z; acc[0][1] = z; acc[1][0] = z; acc[1][1] = z;

  const int srow = wave * 16 + (lane >> 2), scol = (lane & 3) * 8;
  const unsigned short* Ag = A + (long)(bm + srow) * 1024 + scol;
  const unsigned short* Bg = B + (long)(bn + srow) * 1024 + scol;
  unsigned short* Al0 = As + wave * 512;
  unsigned short* Al1 = As + 2048 + wave * 512;
  unsigned short* Bl0 = Bs + wave * 512;
  unsigned short* Bl1 = Bs + 2048 + wave * 512;

  for (int kk = 0; kk < 1024; kk += 64){
    __syncthreads();
    gl_lds16(Ag + kk,      Al0);
    gl_lds16(Ag + kk + 32, Al1);
    gl_lds16(Bg + kk,      Bl0);
    gl_lds16(Bg + kk + 32, Bl1);
    __syncthreads();
#pragma unroll
    for (int half = 0; half < 2; half++){
      const unsigned short* Ah = As + half * 2048;
      const unsigned short* Bh = Bs + half * 2048;
      short8 a0f = *(const short8*)&Ah[(wm + ml) * 32 + quad * 8];
      short8 a1f = *(const short8*)&Ah[(wm + 16 + ml) * 32 + quad * 8];
      short8 b0f = *(const short8*)&Bh[(wn + ml) * 32 + quad * 8];
      short8 b1f = *(const short8*)&Bh[(wn + 16 + ml) * 32 + quad * 8];
      acc[0][0] = MFMA32(a0f, b0f, acc[0][0]);
      acc[0][1] = MFMA32(a0f, b1f, acc[0][1]);
      acc[1][0] = MFMA32(a1f, b0f, acc[1][0]);
      acc[1][1] = MFMA32(a1f, b1f, acc[1][1]);
    }
  }
#pragma unroll
  for (int i = 0; i < 2; i++)
#pragma unroll
    for (int j = 0; j < 2; j++)
#pragma unroll
      for (int r = 0; r < 4; r++)
        C[(long)(bm + wm + i * 16 + quad * 4 + r) * 1024 + bn + wn + j * 16 + ml] = acc[i][j][r];
}

extern "C" void kernel_launch(void* const* d_in, const int* in_sizes, int n_in,
                              void* d_out, int out_size, void* d_ws, size_t ws_size,
                              hipStream_t stream){
  const float* x    = (const float*)d_in[0];
  const float* qw   = (const float*)d_in[1];
  const float* kw   = (const float*)d_in[2];
  const float* vw   = (const float*)d_in[3];
  const float* ow   = (const float*)d_in[4];
  const float* temp = (const float*)d_in[5];
  const float* curv = (const float*)d_in[6];
  float* out = (float*)d_out;

  char* ws = (char*)d_ws;
  size_t off = 0;
  auto alloc = [&](size_t bytes) -> char* {
    char* p = ws + off;
    off += (bytes + 255) & ~(size_t)255;
    return p;
  };
  unsigned short* xb   = (unsigned short*)alloc((size_t)TT * DM * 2);        // 4 MB
  unsigned short* wqkv = (unsigned short*)alloc((size_t)1536 * DM * 2);      // 3 MB
  unsigned short* owb  = (unsigned short*)alloc((size_t)DM * DM * 2);        // 2 MB
  unsigned short* qb   = (unsigned short*)alloc((size_t)NH * TT * HD * 2);   // 4 MB
  unsigned short* kbf  = (unsigned short*)alloc((size_t)NKV * TT * HD * 2);  // 1 MB frag-major K
  unsigned short* vtf  = (unsigned short*)alloc((size_t)NKV * TT * HD * 2);  // 1 MB frag-major V
  float*          q0   = (float*)alloc((size_t)NH * TT * 4);
  float*          k0   = (float*)alloc((size_t)NKV * TT * 4);
  unsigned short* attn = (unsigned short*)alloc((size_t)TT * DM * 2);        // 4 MB
  float*          bpart= (float*)alloc((size_t)768 * 4);

  convertw_kernel<<<4608, 256, 0, stream>>>(x, qw, kw, vw, ow, xb, wqkv, owb);
  gemm1_fused<<<dim3(24, 32), 256, 0, stream>>>(xb, wqkv, qb, kbf, vtf, q0, k0, bpart, curv);
  attn_kernel<<<512, 256, 0, stream>>>(qb, kbf, vtf, q0, k0, temp, curv, attn,
                                       bpart, out + (size_t)TT * DM);
  gemm2_kernel<<<dim3(16, 32), 256, 0, stream>>>(attn, owb, out);
}

// Round 13
// 155.919 us; speedup vs baseline: 1.1621x; 1.1621x over previous
//
#include <hip/hip_runtime.h>
#include <hip/hip_bf16.h>

typedef __attribute__((ext_vector_type(8))) short short8;
typedef __attribute__((ext_vector_type(4))) short bf16x4;
typedef __attribute__((ext_vector_type(4))) float f32x4;

#define TT 2048   // sequence length
#define DM 1024   // model dim
#define NH 16     // query heads
#define NKV 4     // kv heads
#define HD 64     // head dim

#define MFMA32(a,b,c) __builtin_amdgcn_mfma_f32_16x16x32_bf16(a,b,c,0,0,0)
#define MFMA16(a,b,c) __builtin_amdgcn_mfma_f32_16x16x16bf16_1k(a,b,c,0,0,0)

__device__ __forceinline__ unsigned short f2bf(float x){
  unsigned int u = __float_as_uint(x);
  u += 0x7fffu + ((u >> 16) & 1u);   // RNE
  return (unsigned short)(u >> 16);
}
// packed 2xfp32 -> 2xbf16 (v_cvt_pk_bf16_f32 on gfx950)
__device__ __forceinline__ unsigned int pkbf2(float x, float y){
  union { __hip_bfloat162 h; unsigned int u; } t;
  t.h = __float22bfloat162_rn(make_float2(x, y));
  return t.u;
}
// async global->LDS, 16B/lane; per-lane global addr, lds dest = uniform base + lane*16
__device__ __forceinline__ void gl_lds16(const unsigned short* g, unsigned short* l){
  __builtin_amdgcn_global_load_lds(
      (__attribute__((address_space(1))) void*)g,
      (__attribute__((address_space(3))) void*)l, 16, 0, 0);
}

// ---------------- 1. x + weights fp32 -> bf16 ----------------
__global__ __launch_bounds__(256) void convertw_kernel(
    const float* __restrict__ x,
    const float* __restrict__ qw, const float* __restrict__ kw,
    const float* __restrict__ vw, const float* __restrict__ ow,
    unsigned short* __restrict__ xb,
    unsigned short* __restrict__ wqkv, unsigned short* __restrict__ owb){
  long v = (long)blockIdx.x * 256 + threadIdx.x;
  const float* src; unsigned short* dst; long base;
  if      (v < 524288) { src = x;  dst = xb;             base = v; }
  else if (v < 786432) { src = qw; dst = wqkv;           base = v - 524288; }
  else if (v < 851968) { src = kw; dst = wqkv + 1048576; base = v - 786432; }
  else if (v < 917504) { src = vw; dst = wqkv + 1310720; base = v - 851968; }
  else                 { src = ow; dst = owb;            base = v - 917504; }
  f32x4 d = *(const f32x4*)(src + base * 4);
  uint2 pk = { pkbf2(d[0], d[1]), pkbf2(d[2], d[3]) };
  *(uint2*)(dst + base * 4) = pk;
}

// ---------------- 2. QKV GEMM (128x64 tile, async staging) + fused epilogue ----------
// grid dim3(24, 16): x = head-block (0..15 q | 16..19 k | 20..23 v), y = 128-row t-tile
// Wave w computes rows w*32..+32 x all 64 cols (acc[2][4]).
// V written in PV-fragment order: vt[hk][tile16][d=0..63][key16]
__global__ __launch_bounds__(256) void gemm1_fused(
    const unsigned short* __restrict__ xb, const unsigned short* __restrict__ wqkv,
    unsigned short* __restrict__ qb, unsigned short* __restrict__ kb,
    unsigned short* __restrict__ vt,
    float* __restrict__ q0, float* __restrict__ k0,
    float* __restrict__ bpart, const float* __restrict__ curv){
  // union: staging As[2][128][32](16KB) + Bs[2][64][32](8KB) = 24KB; epilogue Ct[128][65] = 33.3KB
  __shared__ __align__(16) char smem[33280];
  unsigned short* As = (unsigned short*)smem;          // 8192 shorts
  unsigned short* Bs = As + 8192;                      // 4096 shorts
  float* Ct = (float*)smem;
  __shared__ float bsum;
  const int tid = threadIdx.x, lane = tid & 63, wave = tid >> 6;
  const int hIdx = blockIdx.x;
  const int bm = blockIdx.y * 128, bn = hIdx * 64;
  const int wm = wave * 32;
  const int ml = lane & 15, quad = lane >> 4;
  if (tid == 0) bsum = 0.f;
  f32x4 acc[2][4];
  const f32x4 z = {0.f, 0.f, 0.f, 0.f};
#pragma unroll
  for (int i = 0; i < 2; i++)
#pragma unroll
    for (int j = 0; j < 4; j++) acc[i][j] = z;

  const int lrow = lane >> 2, lcol = (lane & 3) * 8;
  const unsigned short* AgW = xb   + (long)(bm + wm + lrow) * 1024 + lcol;      // + n*16*1024 + kk + h*32
  const unsigned short* BgW = wqkv + (long)(bn + wave * 16 + lrow) * 1024 + lcol; // + kk + h*32
  unsigned short* AdW = As + wave * 1024;    // + h*4096 + n*512
  unsigned short* BdW = Bs + wave * 512;     // + h*2048

  for (int kk = 0; kk < 1024; kk += 64){
    __syncthreads();
#pragma unroll
    for (int h = 0; h < 2; h++){
      gl_lds16(AgW + kk + h * 32,            AdW + h * 4096);
      gl_lds16(AgW + 16384 + kk + h * 32,    AdW + h * 4096 + 512);
      gl_lds16(BgW + kk + h * 32,            BdW + h * 2048);
    }
    __syncthreads();   // compiler drains vmcnt before barrier
#pragma unroll
    for (int h = 0; h < 2; h++){
      const unsigned short* Ah = As + h * 4096;
      const unsigned short* Bh = Bs + h * 2048;
      short8 a0f = *(const short8*)&Ah[(wm + ml) * 32 + quad * 8];
      short8 a1f = *(const short8*)&Ah[(wm + 16 + ml) * 32 + quad * 8];
      short8 b0f = *(const short8*)&Bh[(     ml) * 32 + quad * 8];
      short8 b1f = *(const short8*)&Bh[(16 + ml) * 32 + quad * 8];
      short8 b2f = *(const short8*)&Bh[(32 + ml) * 32 + quad * 8];
      short8 b3f = *(const short8*)&Bh[(48 + ml) * 32 + quad * 8];
      acc[0][0] = MFMA32(a0f, b0f, acc[0][0]);
      acc[0][1] = MFMA32(a0f, b1f, acc[0][1]);
      acc[0][2] = MFMA32(a0f, b2f, acc[0][2]);
      acc[0][3] = MFMA32(a0f, b3f, acc[0][3]);
      acc[1][0] = MFMA32(a1f, b0f, acc[1][0]);
      acc[1][1] = MFMA32(a1f, b1f, acc[1][1]);
      acc[1][2] = MFMA32(a1f, b2f, acc[1][2]);
      acc[1][3] = MFMA32(a1f, b3f, acc[1][3]);
    }
  }
  __syncthreads();      // staging region -> Ct reuse
#pragma unroll
  for (int i = 0; i < 2; i++)
#pragma unroll
    for (int j = 0; j < 4; j++)
#pragma unroll
      for (int r = 0; r < 4; r++)
        Ct[(wm + i * 16 + quad * 4 + r) * 65 + j * 16 + ml] = acc[i][j][r];
  __syncthreads();

  if (hIdx < 20){
    // RMSNorm + RoPE + q0/k0 (+ spatial partial for q). lane = head-dim d.
    const bool isq = hIdx < 16;
    const int h = isq ? hIdx : hIdx - 16;
    const float c = curv[0];
    unsigned short* ob = isq ? qb : kb;
    float* o0 = isq ? q0 : k0;
#pragma unroll 1
    for (int rr = 0; rr < 32; rr++){
      const int row = wave * 32 + rr;
      const int t = bm + row;
      float val = Ct[row * 65 + lane];
      float ss = val * val;
#pragma unroll
      for (int off = 1; off < 64; off <<= 1) ss += __shfl_xor(ss, off);
      float scale = __builtin_amdgcn_rsqf(ss * (1.f / 64.f) + 1e-6f);
      float xn = val * scale;
      float other = __shfl_xor(xn, 32);
      int fi = lane & 31;
      float ang = (float)t * __builtin_amdgcn_exp2f((float)fi * (-13.287712379549449f / 32.f));
      float sn, cs; __sincosf(ang, &sn, &cs);
      float outv = (lane < 32) ? (xn * cs + other * sn) : (xn * cs - other * sn);
      ob[((long)h * TT + t) * 64 + lane] = f2bf(outv);
      if (lane == 0){
        float sq = ss * scale * scale;      // |normed|^2, rope preserves norm
        o0[h * TT + t] = __builtin_amdgcn_sqrtf(1.f / c + sq);
        if (isq) atomicAdd(&bsum, __builtin_amdgcn_sqrtf(sq));
      }
    }
  } else {
    // V: bf16 + write in PV-fragment order vt[hk][tile16][d][key16]
    const int hk = hIdx - 20;
    const int d = tid >> 2;
#pragma unroll
    for (int half = 0; half < 2; half++){
      const int tseg = (tid & 3) * 16 + half * 64;
      uint4 w0, w1;
      w0.x = pkbf2(Ct[(tseg + 0) * 65 + d], Ct[(tseg + 1) * 65 + d]);
      w0.y = pkbf2(Ct[(tseg + 2) * 65 + d], Ct[(tseg + 3) * 65 + d]);
      w0.z = pkbf2(Ct[(tseg + 4) * 65 + d], Ct[(tseg + 5) * 65 + d]);
      w0.w = pkbf2(Ct[(tseg + 6) * 65 + d], Ct[(tseg + 7) * 65 + d]);
      w1.x = pkbf2(Ct[(tseg + 8) * 65 + d], Ct[(tseg + 9) * 65 + d]);
      w1.y = pkbf2(Ct[(tseg +10) * 65 + d], Ct[(tseg +11) * 65 + d]);
      w1.z = pkbf2(Ct[(tseg +12) * 65 + d], Ct[(tseg +13) * 65 + d]);
      w1.w = pkbf2(Ct[(tseg +14) * 65 + d], Ct[(tseg +15) * 65 + d]);
      const int tile = (bm + tseg) >> 4;
      unsigned short* dst = vt + ((long)(hk * 128 + tile) * 64 + d) * 16;
      *(uint4*)dst = w0;
      *(uint4*)(dst + 8) = w1;
    }
  }
  __syncthreads();
  if (tid == 0) bpart[blockIdx.y * 24 + hIdx] = bsum;
}

// ---------------- 3. head-pair-fused hyperbolic causal attention (R10 proven) ----------
// block = 256 thr (4 waves): one q-tile qt (longest-first), one kvh, heads {h0, h0+1}.
// Each loaded K/V tile feeds BOTH heads. blockIdx&7 = (kvh,hp) for XCD L2 locality.
// S^T = mfma_16x16x32(K,Q): C layout (key=quad*4+r, q=ml) == B-fragment of
// mfma_16x16x16 -> in-lane transform+pack, no cross-lane ops in the loop.
__global__ __launch_bounds__(256, 3) void attn_kernel(
    const unsigned short* __restrict__ qb_, const unsigned short* __restrict__ kb_,
    const unsigned short* __restrict__ vt_,
    const float* __restrict__ q0_, const float* __restrict__ k0_,
    const float* __restrict__ temp, const float* __restrict__ curv,
    unsigned short* __restrict__ attn_out,
    const float* __restrict__ bpart, float* __restrict__ out_scalar){
  __shared__ float lds[8 * 1104];    // regions: wave (head0), 4+wave (head1)
  const int tid = threadIdx.x, lane = tid & 63, wave = tid >> 6;
  const int qt  = 127 - (blockIdx.x >> 3);     // longest-first
  const int sub = blockIdx.x & 7;
  const int kvh = sub >> 1, hp = sub & 1;
  const int h0 = kvh * 4 + hp * 2, h1 = h0 + 1;
  const int i0 = qt * 16;
  const int ml = lane & 15, quad = lane >> 4;
  const float c = curv[0];
  const float rsc = __builtin_amdgcn_rsqf(c);
  const float fac0 = -rsc / temp[h0];
  const float fac1 = -rsc / temp[h1];
  const f32x4 z = {0.f, 0.f, 0.f, 0.f};
  const unsigned short* kh = kb_ + (long)kvh * TT * 64;
  const unsigned short* vh = vt_ + (long)kvh * 128 * 1024;   // [tile16][d][key16]
  const float* k0h = k0_ + kvh * TT;

  short8 qa0 = *(const short8*)&qb_[((long)h0 * TT + i0 + ml) * 64 + quad * 8];
  short8 qa1 = *(const short8*)&qb_[((long)h0 * TT + i0 + ml) * 64 + 32 + quad * 8];
  short8 qb0 = *(const short8*)&qb_[((long)h1 * TT + i0 + ml) * 64 + quad * 8];
  short8 qb1 = *(const short8*)&qb_[((long)h1 * TT + i0 + ml) * 64 + 32 + quad * 8];
  const float q0c0 = c * q0_[h0 * TT + i0 + ml];   // per-lane: q = i0+ml
  const float q0c1 = c * q0_[h1 * TT + i0 + ml];
  const int rowq = i0 + ml;

  f32x4 o0[4], o1[4];
#pragma unroll
  for (int dt = 0; dt < 4; dt++){ o0[dt] = z; o1[dt] = z; }
  float l0 = 0.f, l1 = 0.f;

  const int nt = (i0 + 47) >> 5;   // 32-key tiles

#pragma unroll 1
  for (int t = wave; t < nt; t += 4){
    const int j0 = t << 5;
    const unsigned short* kp = kh + (long)j0 * 64;
    short8 ka0 = *(const short8*)(kp + ml * 64 + quad * 8);
    short8 ka1 = *(const short8*)(kp + ml * 64 + 32 + quad * 8);
    short8 kc0 = *(const short8*)(kp + (16 + ml) * 64 + quad * 8);
    short8 kc1 = *(const short8*)(kp + (16 + ml) * 64 + 32 + quad * 8);
    f32x4 k0a = *(const f32x4*)(k0h + j0 + quad * 4);
    f32x4 k0b = *(const f32x4*)(k0h + j0 + 16 + quad * 4);
    const unsigned short* vpa = vh + (long)(j0 >> 4) * 1024;
    bf16x4 vfa0 = *(const bf16x4*)(vpa + ( 0 + ml) * 16 + quad * 4);
    bf16x4 vfa1 = *(const bf16x4*)(vpa + (16 + ml) * 16 + quad * 4);
    bf16x4 vfa2 = *(const bf16x4*)(vpa + (32 + ml) * 16 + quad * 4);
    bf16x4 vfa3 = *(const bf16x4*)(vpa + (48 + ml) * 16 + quad * 4);
    bf16x4 vfb0 = *(const bf16x4*)(vpa + 1024 + ( 0 + ml) * 16 + quad * 4);
    bf16x4 vfb1 = *(const bf16x4*)(vpa + 1024 + (16 + ml) * 16 + quad * 4);
    bf16x4 vfb2 = *(const bf16x4*)(vpa + 1024 + (32 + ml) * 16 + quad * 4);
    bf16x4 vfb3 = *(const bf16x4*)(vpa + 1024 + (48 + ml) * 16 + quad * 4);

    const int keyb = j0 + quad * 4;
    const bool nm = (j0 + 31 > i0);
    // ---- head 0 ----
    {
      f32x4 s0 = z, s1 = z;
      s0 = MFMA32(ka0, qa0, s0);
      s0 = MFMA32(ka1, qa1, s0);
      s1 = MFMA32(kc0, qa0, s1);
      s1 = MFMA32(kc1, qa1, s1);
      float p0[4], p1[4];
#pragma unroll
      for (int r = 0; r < 4; r++){
        float argA = fmaxf(__builtin_fmaf(-c, s0[r], q0c0 * k0a[r]), 1.00001f);
        float wA   = argA + __builtin_amdgcn_sqrtf(__builtin_fmaf(argA, argA, -1.f));
        float pA   = __builtin_amdgcn_exp2f(fac0 * __builtin_amdgcn_logf(wA));
        float argB = fmaxf(__builtin_fmaf(-c, s1[r], q0c0 * k0b[r]), 1.00001f);
        float wB   = argB + __builtin_amdgcn_sqrtf(__builtin_fmaf(argB, argB, -1.f));
        float pB   = __builtin_amdgcn_exp2f(fac0 * __builtin_amdgcn_logf(wB));
        if (nm){
          if (keyb + r > rowq)      pA = 0.f;
          if (keyb + 16 + r > rowq) pB = 0.f;
        }
        p0[r] = pA; p1[r] = pB;
        l0 += pA + pB;
      }
      uint2 pua = { pkbf2(p0[0], p0[1]), pkbf2(p0[2], p0[3]) };
      uint2 pub = { pkbf2(p1[0], p1[1]), pkbf2(p1[2], p1[3]) };
      bf16x4 pfa = *(bf16x4*)&pua;
      bf16x4 pfb = *(bf16x4*)&pub;
      o0[0] = MFMA16(vfa0, pfa, o0[0]);
      o0[1] = MFMA16(vfa1, pfa, o0[1]);
      o0[2] = MFMA16(vfa2, pfa, o0[2]);
      o0[3] = MFMA16(vfa3, pfa, o0[3]);
      o0[0] = MFMA16(vfb0, pfb, o0[0]);
      o0[1] = MFMA16(vfb1, pfb, o0[1]);
      o0[2] = MFMA16(vfb2, pfb, o0[2]);
      o0[3] = MFMA16(vfb3, pfb, o0[3]);
    }
    // ---- head 1 (same K/V tile) ----
    {
      f32x4 s0 = z, s1 = z;
      s0 = MFMA32(ka0, qb0, s0);
      s0 = MFMA32(ka1, qb1, s0);
      s1 = MFMA32(kc0, qb0, s1);
      s1 = MFMA32(kc1, qb1, s1);
      float p0[4], p1[4];
#pragma unroll
      for (int r = 0; r < 4; r++){
        float argA = fmaxf(__builtin_fmaf(-c, s0[r], q0c1 * k0a[r]), 1.00001f);
        float wA   = argA + __builtin_amdgcn_sqrtf(__builtin_fmaf(argA, argA, -1.f));
        float pA   = __builtin_amdgcn_exp2f(fac1 * __builtin_amdgcn_logf(wA));
        float argB = fmaxf(__builtin_fmaf(-c, s1[r], q0c1 * k0b[r]), 1.00001f);
        float wB   = argB + __builtin_amdgcn_sqrtf(__builtin_fmaf(argB, argB, -1.f));
        float pB   = __builtin_amdgcn_exp2f(fac1 * __builtin_amdgcn_logf(wB));
        if (nm){
          if (keyb + r > rowq)      pA = 0.f;
          if (keyb + 16 + r > rowq) pB = 0.f;
        }
        p0[r] = pA; p1[r] = pB;
        l1 += pA + pB;
      }
      uint2 pua = { pkbf2(p0[0], p0[1]), pkbf2(p0[2], p0[3]) };
      uint2 pub = { pkbf2(p1[0], p1[1]), pkbf2(p1[2], p1[3]) };
      bf16x4 pfa = *(bf16x4*)&pua;
      bf16x4 pfb = *(bf16x4*)&pub;
      o1[0] = MFMA16(vfa0, pfa, o1[0]);
      o1[1] = MFMA16(vfa1, pfa, o1[1]);
      o1[2] = MFMA16(vfa2, pfa, o1[2]);
      o1[3] = MFMA16(vfa3, pfa, o1[3]);
      o1[0] = MFMA16(vfb0, pfb, o1[0]);
      o1[1] = MFMA16(vfb1, pfb, o1[1]);
      o1[2] = MFMA16(vfb2, pfb, o1[2]);
      o1[3] = MFMA16(vfb3, pfb, o1[3]);
    }
  }
  // l across quads (keys split over quads/regs; q=ml fixed)
  l0 += __shfl_xor(l0, 16); l0 += __shfl_xor(l0, 32);
  l1 += __shfl_xor(l1, 16); l1 += __shfl_xor(l1, 32);
  // publish wave partials: O^T reg r -> d = dt*16+quad*4+r at q=ml
  {
    float* w0 = lds + wave * 1104;
    float* w1 = lds + (4 + wave) * 1104;
#pragma unroll
    for (int dt = 0; dt < 4; dt++){
      *(f32x4*)&w0[ml * 68 + dt * 16 + quad * 4] = o0[dt];
      *(f32x4*)&w1[ml * 68 + dt * 16 + quad * 4] = o1[dt];
    }
    if (quad == 0){ w0[1088 + ml] = l0; w1[1088 + ml] = l1; }
  }
  __syncthreads();
  // merge 4 waves per head: thread -> (row = tid>>4, 4 d's)
  {
    const int row = tid >> 4, c0 = (tid & 15) * 4;
#pragma unroll 1
    for (int hb = 0; hb < 2; hb++){
      const float* base = lds + hb * 4 * 1104;
      float L = 0.f; f32x4 s = z;
#pragma unroll
      for (int w = 0; w < 4; w++){
        const float* rg = base + w * 1104;
        L += rg[1088 + row];
        f32x4 t2 = *(const f32x4*)&rg[row * 68 + c0];
        s[0] += t2[0]; s[1] += t2[1]; s[2] += t2[2]; s[3] += t2[3];
      }
      float invL = __builtin_amdgcn_rcpf(L);
      const int h = hb ? h1 : h0;
      uint2 o = { pkbf2(s[0] * invL, s[1] * invL), pkbf2(s[2] * invL, s[3] * invL) };
      *(uint2*)&attn_out[(long)(i0 + row) * 1024 + h * 64 + c0] = o;
    }
  }
  // fused spatial_norm finalize
  if (blockIdx.x == 0 && tid < 64){
    float s = 0.f;
    for (int i = lane; i < 384; i += 64) s += bpart[i];
#pragma unroll
    for (int off = 1; off < 64; off <<= 1) s += __shfl_xor(s, off);
    if (lane == 0) out_scalar[0] = s * (1.f / 32768.f);
  }
}

// ---------------- 4. O-proj GEMM (128x64 tile, async staging): out = attn x owb^T -----
// grid dim3(16, 16): 256 blocks = 1/CU exact. Wave w: rows w*32..+32 x 64 cols.
__global__ __launch_bounds__(256) void gemm2_kernel(
    const unsigned short* __restrict__ A, const unsigned short* __restrict__ B,
    float* __restrict__ C){
  __shared__ __align__(16) unsigned short As[2 * 128 * 32];  // 16KB
  __shared__ __align__(16) unsigned short Bs[2 * 64 * 32];   // 8KB
  const int tid = threadIdx.x, lane = tid & 63, wave = tid >> 6;
  const int bm = blockIdx.y * 128, bn = blockIdx.x * 64;
  const int wm = wave * 32;
  const int ml = lane & 15, quad = lane >> 4;
  f32x4 acc[2][4];
  const f32x4 z = {0.f, 0.f, 0.f, 0.f};
#pragma unroll
  for (int i = 0; i < 2; i++)
#pragma unroll
    for (int j = 0; j < 4; j++) acc[i][j] = z;

  const int lrow = lane >> 2, lcol = (lane & 3) * 8;
  const unsigned short* AgW = A + (long)(bm + wm + lrow) * 1024 + lcol;
  const unsigned short* BgW = B + (long)(bn + wave * 16 + lrow) * 1024 + lcol;
  unsigned short* AdW = As + wave * 1024;
  unsigned short* BdW = Bs + wave * 512;

  for (int kk = 0; kk < 1024; kk += 64){
    __syncthreads();
#pragma unroll
    for (int h = 0; h < 2; h++){
      gl_lds16(AgW + kk + h * 32,         AdW + h * 4096);
      gl_lds16(AgW + 16384 + kk + h * 32, AdW + h * 4096 + 512);
      gl_lds16(BgW + kk + h * 32,         BdW + h * 2048);
    }
    __syncthreads();
#pragma unroll
    for (int h = 0; h < 2; h++){
      const unsigned short* Ah = As + h * 4096;
      const unsigned short* Bh = Bs + h * 2048;
      short8 a0f = *(const short8*)&Ah[(wm + ml) * 32 + quad * 8];
      short8 a1f = *(const short8*)&Ah[(wm + 16 + ml) * 32 + quad * 8];
      short8 b0f = *(const short8*)&Bh[(     ml) * 32 + quad * 8];
      short8 b1f = *(const short8*)&Bh[(16 + ml) * 32 + quad * 8];
      short8 b2f = *(const short8*)&Bh[(32 + ml) * 32 + quad * 8];
      short8 b3f = *(const short8*)&Bh[(48 + ml) * 32 + quad * 8];
      acc[0][0] = MFMA32(a0f, b0f, acc[0][0]);
      acc[0][1] = MFMA32(a0f, b1f, acc[0][1]);
      acc[0][2] = MFMA32(a0f, b2f, acc[0][2]);
      acc[0][3] = MFMA32(a0f, b3f, acc[0][3]);
      acc[1][0] = MFMA32(a1f, b0f, acc[1][0]);
      acc[1][1] = MFMA32(a1f, b1f, acc[1][1]);
      acc[1][2] = MFMA32(a1f, b2f, acc[1][2]);
      acc[1][3] = MFMA32(a1f, b3f, acc[1][3]);
    }
  }
#pragma unroll
  for (int i = 0; i < 2; i++)
#pragma unroll
    for (int j = 0; j < 4; j++)
#pragma unroll
      for (int r = 0; r < 4; r++)
        C[(long)(bm + wm + i * 16 + quad * 4 + r) * 1024 + bn + j * 16 + ml] = acc[i][j][r];
}

extern "C" void kernel_launch(void* const* d_in, const int* in_sizes, int n_in,
                              void* d_out, int out_size, void* d_ws, size_t ws_size,
                              hipStream_t stream){
  const float* x    = (const float*)d_in[0];
  const float* qw   = (const float*)d_in[1];
  const float* kw   = (const float*)d_in[2];
  const float* vw   = (const float*)d_in[3];
  const float* ow   = (const float*)d_in[4];
  const float* temp = (const float*)d_in[5];
  const float* curv = (const float*)d_in[6];
  float* out = (float*)d_out;

  char* ws = (char*)d_ws;
  size_t off = 0;
  auto alloc = [&](size_t bytes) -> char* {
    char* p = ws + off;
    off += (bytes + 255) & ~(size_t)255;
    return p;
  };
  unsigned short* xb   = (unsigned short*)alloc((size_t)TT * DM * 2);        // 4 MB
  unsigned short* wqkv = (unsigned short*)alloc((size_t)1536 * DM * 2);      // 3 MB
  unsigned short* owb  = (unsigned short*)alloc((size_t)DM * DM * 2);        // 2 MB
  unsigned short* qb   = (unsigned short*)alloc((size_t)NH * TT * HD * 2);   // 4 MB
  unsigned short* kb   = (unsigned short*)alloc((size_t)NKV * TT * HD * 2);  // 1 MB row-major K
  unsigned short* vt   = (unsigned short*)alloc((size_t)NKV * TT * HD * 2);  // 1 MB tile-swizzled V
  float*          q0   = (float*)alloc((size_t)NH * TT * 4);
  float*          k0   = (float*)alloc((size_t)NKV * TT * 4);
  unsigned short* attn = (unsigned short*)alloc((size_t)TT * DM * 2);        // 4 MB
  float*          bpart= (float*)alloc((size_t)384 * 4);

  convertw_kernel<<<4608, 256, 0, stream>>>(x, qw, kw, vw, ow, xb, wqkv, owb);
  gemm1_fused<<<dim3(24, 16), 256, 0, stream>>>(xb, wqkv, qb, kb, vt, q0, k0, bpart, curv);
  attn_kernel<<<1024, 256, 0, stream>>>(qb, kb, vt, q0, k0, temp, curv, attn,
                                        bpart, out + (size_t)TT * DM);
  gemm2_kernel<<<dim3(16, 16), 256, 0, stream>>>(attn, owb, out);
}